// Round 12
// baseline (213.187 us; speedup 1.0000x reference)
//
#include <hip/hip_runtime.h>
#include <hip/hip_bf16.h>
#include <stdint.h>
#include <stddef.h>

#define DEVI __device__ __forceinline__

typedef __attribute__((ext_vector_type(8)))  short bf16x8;
typedef __attribute__((ext_vector_type(4)))  float f32x4;
typedef __attribute__((ext_vector_type(16))) float f32x16;
typedef __attribute__((ext_vector_type(2)))  unsigned u32x2;
typedef __attribute__((ext_vector_type(4)))  unsigned u32x4;

DEVI unsigned short f2bf(float f) {
    __hip_bfloat16 h = __float2bfloat16(f);   // RNE
    union { __hip_bfloat16 h; unsigned short u; } v; v.h = h; return v.u;
}
// paired convert -> single v_cvt_pk_bf16_f32 (lo in bits[15:0])
DEVI unsigned pk2(float lo, float hi) {
    union { __hip_bfloat162 h2; unsigned u; } v;
    v.h2 = __float22bfloat162_rn(float2{lo, hi});
    return v.u;
}
DEVI f32x4 zero4() { f32x4 z; z[0] = z[1] = z[2] = z[3] = 0.f; return z; }
DEVI f32x16 zero16() {
    f32x16 z;
#pragma unroll
    for (int i = 0; i < 16; ++i) z[i] = 0.f;
    return z;
}

// ---------------------------------------------------------------------------
// ws layout:
//   qbf [1024][64][256] bf16 @ 0           natural
//   kbf [2048][64][256] bf16 @ 33554432    natural
//   vbf [2048][64][256] bf16 @ 100663296   natural
//   partial [4][4096][128] f32 @ 167772160
//   pbf [4096][128] bf16 @ 176160768
// ---------------------------------------------------------------------------
// proj v6 = r11 structure at HALF-IMAGE granularity for occupancy:
//   block = 128 px x 64 ch; LDS 16.9 KB; VGPR<=64 via launch_bounds(256,8)
//   -> target 8 blocks/CU (32 waves, ~100% occ; r11 measured 37%).
//   - X staged TRANSPOSED [p][c] (stride 66) via per-thread 4x4 reg transpose
//     (nt loads); wave w stages & reads only p-band [w*32,+32) -> zero barriers
//   - A-frag = one ds_read_b128; row-permuted so lane owns 8 contiguous px
//   - direct u32x4 stores (full 64B lines); paired cvt via v_cvt_pk_bf16_f32
// ---------------------------------------------------------------------------

#define TS 66   // transposed X stride in shorts: [128 p][66]

DEVI void load_wfrags(const float* __restrict__ W, const float* __restrict__ B,
                      int l15, int lg, bf16x8 (&bf)[4][2], float (&bias)[4]) {
#pragma unroll
    for (int ot = 0; ot < 4; ++ot) {
        const int o = ot * 16 + l15;
        bias[ot] = B[o];
#pragma unroll
        for (int ks = 0; ks < 2; ++ks) {
            const float* wp = W + o * 64 + ks * 32 + lg * 8;
            f32x4 w0 = *(const f32x4*)wp, w1 = *(const f32x4*)(wp + 4);
            union { bf16x8 a; u32x4 u; } cv;
            cv.u[0] = pk2(w0[0], w0[1]);
            cv.u[1] = pk2(w0[2], w0[3]);
            cv.u[2] = pk2(w1[0], w1[1]);
            cv.u[3] = pk2(w1[2], w1[3]);
            bf[ot][ks] = cv.a;
        }
    }
}

// 16 MFMA -> 4 dwordx4 full-line stores (half-image wave: 32 px x 64 out)
DEVI void emit_half(const bf16x8 (&afr)[2][2], const bf16x8 (&bf)[4][2],
                    const float (&bias)[4], int w, int l15, int lg,
                    unsigned short* __restrict__ og) {
#pragma unroll
    for (int ot = 0; ot < 4; ++ot) {
        f32x4 a0 = zero4(), a1 = zero4();
        a0 = __builtin_amdgcn_mfma_f32_16x16x32_bf16(afr[0][0], bf[ot][0], a0, 0, 0, 0);
        a0 = __builtin_amdgcn_mfma_f32_16x16x32_bf16(afr[0][1], bf[ot][1], a0, 0, 0, 0);
        a1 = __builtin_amdgcn_mfma_f32_16x16x32_bf16(afr[1][0], bf[ot][0], a1, 0, 0, 0);
        a1 = __builtin_amdgcn_mfma_f32_16x16x32_bf16(afr[1][1], bf[ot][1], a1, 0, 0, 0);
        const float b = bias[ot];
        u32x4 sv;
        sv[0] = pk2(a0[0] + b, a0[1] + b);
        sv[1] = pk2(a0[2] + b, a0[3] + b);
        sv[2] = pk2(a1[0] + b, a1[1] + b);
        sv[3] = pk2(a1[2] + b, a1[3] + b);
        *(u32x4*)(og + (size_t)(ot * 16 + l15) * 256 + w * 32 + lg * 8) = sv;
    }
}

// ============================ unified proj ============================
// blocks 0..4095: kv half-images (img=bid>>1, half=bid&1); 4096..6143: q halves
__global__ __launch_bounds__(256, 8) void proj_kernel(
    const float* __restrict__ qq, const float* __restrict__ kvg,
    const float* __restrict__ Wq, const float* __restrict__ bq,
    const float* __restrict__ Wk, const float* __restrict__ bk,
    const float* __restrict__ Wv, const float* __restrict__ bv,
    unsigned short* __restrict__ qbf, unsigned short* __restrict__ kbf,
    unsigned short* __restrict__ vbf)
{
    __shared__ unsigned short XT[128 * TS];   // [p][c] transposed, 16.9 KB
    const int tid = threadIdx.x;
    const int w = tid >> 6, lane = tid & 63;
    const int l15 = lane & 15, lg = lane >> 4;
    const int l7 = lane & 7, lh8 = lane >> 3;
    const int bid = blockIdx.x;
    const bool dual = (bid < 4096);

    const float* xg;
    unsigned short* o1;
    unsigned short* o2 = nullptr;
    if (dual) {
        const int img = bid >> 1, half = bid & 1;
        xg = kvg + (size_t)img * 16384 + half * 128;
        o1 = kbf + (size_t)img * 16384 + half * 128;
        o2 = vbf + (size_t)img * 16384 + half * 128;
    } else {
        const int n = bid - 4096;
        const int img = n >> 1, half = n & 1;
        xg = qq + (size_t)img * 16384 + half * 128;
        o1 = qbf + (size_t)img * 16384 + half * 128;
    }

    bf16x8 bf1[4][2]; float bias1[4];
    load_wfrags(dual ? Wk : Wq, dual ? bk : bq, l15, lg, bf1, bias1);

    // stage X -> XT[p][c] (local p in [0,128)); wave w owns p-band [w*32,+32)
    const int pq = w * 32 + l7 * 4;           // this thread's pixel quad
#pragma unroll
    for (int it = 0; it < 2; ++it) {
        const int c0 = it * 32 + lh8 * 4;
        f32x4 r0 = __builtin_nontemporal_load((const f32x4*)(xg + (size_t)(c0 + 0) * 256 + pq));
        f32x4 r1 = __builtin_nontemporal_load((const f32x4*)(xg + (size_t)(c0 + 1) * 256 + pq));
        f32x4 r2 = __builtin_nontemporal_load((const f32x4*)(xg + (size_t)(c0 + 2) * 256 + pq));
        f32x4 r3 = __builtin_nontemporal_load((const f32x4*)(xg + (size_t)(c0 + 3) * 256 + pq));
#pragma unroll
        for (int j = 0; j < 4; ++j) {
            u32x2 dd;
            dd[0] = pk2(r0[j], r1[j]);
            dd[1] = pk2(r2[j], r3[j]);
            *(u32x2*)(&XT[(pq + j) * TS + c0]) = dd;
        }
    }
    // NO barrier: wave w staged exactly the p-band it reads below.

    // A-frags [u][ks], row-permuted: prow = w*32 + (l15>>2)*8 + u*4 + (l15&3)
    // -> D element r of (l15,lg) = pixel w*32 + lg*8 + u*4 + r (8 contiguous px)
    bf16x8 afr[2][2];
#pragma unroll
    for (int u = 0; u < 2; ++u) {
        const int prow = w * 32 + (l15 >> 2) * 8 + u * 4 + (l15 & 3);
#pragma unroll
        for (int ks = 0; ks < 2; ++ks)
            afr[u][ks] = *(const bf16x8*)(&XT[prow * TS + ks * 32 + lg * 8]);
    }

    emit_half(afr, bf1, bias1, w, l15, lg, o1);
    if (dual) {
        load_wfrags(Wv, bv, l15, lg, bf1, bias1);   // reuse regs, L2-hot
        emit_half(afr, bf1, bias1, w, l15, lg, o2);
    }
}

// ============================ sim (Q.K^T partials, K-split x4) ============================
// r1/r5-proven version: grid 256 = (bh 64) x (ks 4); block 128 (2 waves)
__global__ __launch_bounds__(128) void sim_kernel(
    const unsigned short* __restrict__ qbf, const unsigned short* __restrict__ kbf,
    float* __restrict__ partial)
{
    const int tid = threadIdx.x;
    const int w = tid >> 6, lane = tid & 63;
    const int l31 = lane & 31, lh = lane >> 5;
    const int bh = blockIdx.x & 63, ks = blockIdx.x >> 6;
    const int b = bh >> 2, head = bh & 3;
    const int t0 = w * 64;

    const unsigned short* qbase = qbf + (size_t)b * 64 * 16384 + head * 4096;
    const unsigned short* kbase = kbf + (size_t)b * 128 * 16384 + head * 4096;

    f32x16 acc00 = zero16(), acc01 = zero16(), acc10 = zero16(), acc11 = zero16();
    const int kk0 = ks * 1024;
    for (int kk = 0; kk < 64; ++kk) {
        int k = kk0 + kk * 16 + lh * 8;
        bf16x8 a0 = *(const bf16x8*)(qbase + (size_t)(l31)      * 16384 + k);
        bf16x8 a1 = *(const bf16x8*)(qbase + (size_t)(l31 + 32) * 16384 + k);
        bf16x8 b0 = *(const bf16x8*)(kbase + (size_t)(t0 + l31)      * 16384 + k);
        bf16x8 b1 = *(const bf16x8*)(kbase + (size_t)(t0 + 32 + l31) * 16384 + k);
        acc00 = __builtin_amdgcn_mfma_f32_32x32x16_bf16(a0, b0, acc00, 0, 0, 0);
        acc01 = __builtin_amdgcn_mfma_f32_32x32x16_bf16(a0, b1, acc01, 0, 0, 0);
        acc10 = __builtin_amdgcn_mfma_f32_32x32x16_bf16(a1, b0, acc10, 0, 0, 0);
        acc11 = __builtin_amdgcn_mfma_f32_32x32x16_bf16(a1, b1, acc11, 0, 0, 0);
    }

    float* pb = partial + ((size_t)ks * 4096 + (size_t)bh * 64) * 128;
#pragma unroll
    for (int r = 0; r < 16; ++r) {
        int kqr = (r & 3) + 8 * (r >> 2) + 4 * lh;
        pb[(kqr)      * 128 + t0 + l31]      = acc00[r];
        pb[(kqr)      * 128 + t0 + 32 + l31] = acc01[r];
        pb[(kqr + 32) * 128 + t0 + l31]      = acc10[r];
        pb[(kqr + 32) * 128 + t0 + 32 + l31] = acc11[r];
    }
}

// ============================ softmax ============================
__global__ __launch_bounds__(256) void softmax_kernel(
    const float* __restrict__ partial, float* __restrict__ sim_out,
    unsigned short* __restrict__ pbf)
{
    const int tid = threadIdx.x;
    const int w = tid >> 6, lane = tid & 63;
    const int row = blockIdx.x * 4 + w;

    float x0 = 0.f, x1 = 0.f;
#pragma unroll
    for (int s = 0; s < 4; ++s) {
        x0 += partial[((size_t)s * 4096 + row) * 128 + lane];
        x1 += partial[((size_t)s * 4096 + row) * 128 + 64 + lane];
    }
    const float scale = 1.0f / 64.0f;
    x0 *= scale; x1 *= scale;
    float m = fmaxf(x0, x1);
#pragma unroll
    for (int off = 32; off; off >>= 1) m = fmaxf(m, __shfl_xor(m, off));
    float e0 = __expf(x0 - m), e1 = __expf(x1 - m);
    float s = e0 + e1;
#pragma unroll
    for (int off = 32; off; off >>= 1) s += __shfl_xor(s, off);
    float inv = 1.0f / s;
    float p0 = e0 * inv, p1 = e1 * inv;
    sim_out[(size_t)row * 128 + lane]      = p0;
    sim_out[(size_t)row * 128 + 64 + lane] = p1;
    pbf[(size_t)row * 128 + lane]      = f2bf(p0);
    pbf[(size_t)row * 128 + 64 + lane] = f2bf(p1);
}

// ============================ PV (natural V, transpose-on-read) ============================
__global__ __launch_bounds__(256) void pv_kernel(
    const unsigned short* __restrict__ pbf, const unsigned short* __restrict__ vbf,
    float* __restrict__ outp)
{
    const int tid = threadIdx.x;
    const int w = tid >> 6, lane = tid & 63;
    const int l31 = lane & 31, lh = lane >> 5;
    const int bh = blockIdx.x >> 4, cb = blockIdx.x & 15;
    const int b = bh >> 2, h = bh & 3;
    const int ch = h * 16 + cb;
    const int p0 = w * 64;

    const unsigned short* pb = pbf + (size_t)bh * 64 * 128;
    const unsigned short* vb = vbf + (size_t)b * 128 * 16384 + (size_t)ch * 256;

    f32x16 acc00 = zero16(), acc01 = zero16(), acc10 = zero16(), acc11 = zero16();
    for (int kk = 0; kk < 8; ++kk) {
        const int t0 = kk * 16;
        bf16x8 a0 = *(const bf16x8*)(pb + (size_t)l31 * 128 + t0 + lh * 8);
        bf16x8 a1 = *(const bf16x8*)(pb + (size_t)(l31 + 32) * 128 + t0 + lh * 8);
        bf16x8 b0, b1;
#pragma unroll
        for (int j = 0; j < 8; ++j) {
            const unsigned short* vr = vb + (size_t)(t0 + lh * 8 + j) * 16384;
            b0[j] = (short)vr[p0 + l31];
            b1[j] = (short)vr[p0 + 32 + l31];
        }
        acc00 = __builtin_amdgcn_mfma_f32_32x32x16_bf16(a0, b0, acc00, 0, 0, 0);
        acc01 = __builtin_amdgcn_mfma_f32_32x32x16_bf16(a0, b1, acc01, 0, 0, 0);
        acc10 = __builtin_amdgcn_mfma_f32_32x32x16_bf16(a1, b0, acc10, 0, 0, 0);
        acc11 = __builtin_amdgcn_mfma_f32_32x32x16_bf16(a1, b1, acc11, 0, 0, 0);
    }

    float* ob = outp + (size_t)b * 64 * 16384 + (size_t)ch * 256;
#pragma unroll
    for (int r = 0; r < 16; ++r) {
        int kqr = (r & 3) + 8 * (r >> 2) + 4 * lh;
        ob[(size_t)(kqr)      * 16384 + p0 + l31]      = acc00[r];
        ob[(size_t)(kqr)      * 16384 + p0 + 32 + l31] = acc01[r];
        ob[(size_t)(kqr + 32) * 16384 + p0 + l31]      = acc10[r];
        ob[(size_t)(kqr + 32) * 16384 + p0 + 32 + l31] = acc11[r];
    }
}

// ============================ launch ============================
extern "C" void kernel_launch(void* const* d_in, const int* in_sizes, int n_in,
                              void* d_out, int out_size, void* d_ws, size_t ws_size,
                              hipStream_t stream)
{
    const float* qq = (const float*)d_in[0];
    const float* kv = (const float*)d_in[1];
    const float* Wq = (const float*)d_in[2];
    const float* bq = (const float*)d_in[3];
    const float* Wk = (const float*)d_in[4];
    const float* bk = (const float*)d_in[5];
    const float* Wv = (const float*)d_in[6];
    const float* bv = (const float*)d_in[7];

    float* outp    = (float*)d_out;
    float* sim_out = outp + (size_t)16777216;

    char* ws = (char*)d_ws;
    unsigned short* qbf     = (unsigned short*)(ws);
    unsigned short* kbf     = (unsigned short*)(ws + 33554432);
    unsigned short* vbf     = (unsigned short*)(ws + 100663296);
    float*          partial = (float*)         (ws + 167772160);
    unsigned short* pbf     = (unsigned short*)(ws + 176160768);
    (void)in_sizes; (void)n_in; (void)out_size; (void)ws_size;

    proj_kernel   <<<dim3(6144), dim3(256), 0, stream>>>(qq, kv, Wq, bq, Wk, bk, Wv, bv,
                                                         qbf, kbf, vbf);
    sim_kernel    <<<dim3(256),  dim3(128), 0, stream>>>(qbf, kbf, partial);
    softmax_kernel<<<dim3(1024), dim3(256), 0, stream>>>(partial, sim_out, pbf);
    pv_kernel     <<<dim3(1024), dim3(256), 0, stream>>>(pbf, vbf, outp);
}

// Round 13
// 155.816 us; speedup vs baseline: 1.3682x; 1.3682x over previous
//
#include <hip/hip_runtime.h>
#include <hip/hip_bf16.h>
#include <stdint.h>
#include <stddef.h>

#define DEVI __device__ __forceinline__

typedef __attribute__((ext_vector_type(8)))  short bf16x8;
typedef __attribute__((ext_vector_type(4)))  float f32x4;
typedef __attribute__((ext_vector_type(16))) float f32x16;
typedef __attribute__((ext_vector_type(2)))  unsigned u32x2;
typedef __attribute__((ext_vector_type(4)))  unsigned u32x4;

DEVI unsigned short f2bf(float f) {
    __hip_bfloat16 h = __float2bfloat16(f);   // RNE
    union { __hip_bfloat16 h; unsigned short u; } v; v.h = h; return v.u;
}
// paired convert -> single v_cvt_pk_bf16_f32 (lo in bits[15:0])
DEVI unsigned pk2(float lo, float hi) {
    union { __hip_bfloat162 h2; unsigned u; } v;
    v.h2 = __float22bfloat162_rn(float2{lo, hi});
    return v.u;
}
DEVI f32x4 zero4() { f32x4 z; z[0] = z[1] = z[2] = z[3] = 0.f; return z; }
DEVI f32x16 zero16() {
    f32x16 z;
#pragma unroll
    for (int i = 0; i < 16; ++i) z[i] = 0.f;
    return z;
}

// ---------------------------------------------------------------------------
// ws layout:
//   qbf [1024][64][256] bf16 @ 0           natural
//   kbf [2048][64][256] bf16 @ 33554432    natural
//   vbf [2048][64][256] bf16 @ 100663296   natural
//   partial [4][4096][128] f32 @ 167772160
//   pbf [4096][128] bf16 @ 176160768
// ---------------------------------------------------------------------------
// proj v7 = r12 half-image structure WITHOUT the forced wave bound.
//   r12's __launch_bounds__(256,8) forced 32 VGPR -> scratch spills
//   (WRITE 350MB, FETCH +66MB). Natural allocation is ~56-60 VGPR ->
//   8 waves/SIMD by VGPR, 9 blocks/CU by LDS (16.9 KB) -> high occupancy
//   with zero spill.
//   - X staged TRANSPOSED [p][c] (stride 66), per-thread 4x4 reg transpose
//     (nt loads); wave w owns p-band [w*32,+32) -> zero barriers
//   - A-frag = one ds_read_b128; row-permuted so lane owns 8 contiguous px
//   - direct u32x4 stores (full 64B lines); paired cvt via v_cvt_pk_bf16_f32
// ---------------------------------------------------------------------------

#define TS 66   // transposed X stride in shorts: [128 p][66]

DEVI void load_wfrags(const float* __restrict__ W, const float* __restrict__ B,
                      int l15, int lg, bf16x8 (&bf)[4][2], float (&bias)[4]) {
#pragma unroll
    for (int ot = 0; ot < 4; ++ot) {
        const int o = ot * 16 + l15;
        bias[ot] = B[o];
#pragma unroll
        for (int ks = 0; ks < 2; ++ks) {
            const float* wp = W + o * 64 + ks * 32 + lg * 8;
            f32x4 w0 = *(const f32x4*)wp, w1 = *(const f32x4*)(wp + 4);
            union { bf16x8 a; u32x4 u; } cv;
            cv.u[0] = pk2(w0[0], w0[1]);
            cv.u[1] = pk2(w0[2], w0[3]);
            cv.u[2] = pk2(w1[0], w1[1]);
            cv.u[3] = pk2(w1[2], w1[3]);
            bf[ot][ks] = cv.a;
        }
    }
}

// 16 MFMA -> 4 dwordx4 full-line stores (half-image wave: 32 px x 64 out)
DEVI void emit_half(const bf16x8 (&afr)[2][2], const bf16x8 (&bf)[4][2],
                    const float (&bias)[4], int w, int l15, int lg,
                    unsigned short* __restrict__ og) {
#pragma unroll
    for (int ot = 0; ot < 4; ++ot) {
        f32x4 a0 = zero4(), a1 = zero4();
        a0 = __builtin_amdgcn_mfma_f32_16x16x32_bf16(afr[0][0], bf[ot][0], a0, 0, 0, 0);
        a0 = __builtin_amdgcn_mfma_f32_16x16x32_bf16(afr[0][1], bf[ot][1], a0, 0, 0, 0);
        a1 = __builtin_amdgcn_mfma_f32_16x16x32_bf16(afr[1][0], bf[ot][0], a1, 0, 0, 0);
        a1 = __builtin_amdgcn_mfma_f32_16x16x32_bf16(afr[1][1], bf[ot][1], a1, 0, 0, 0);
        const float b = bias[ot];
        u32x4 sv;
        sv[0] = pk2(a0[0] + b, a0[1] + b);
        sv[1] = pk2(a0[2] + b, a0[3] + b);
        sv[2] = pk2(a1[0] + b, a1[1] + b);
        sv[3] = pk2(a1[2] + b, a1[3] + b);
        *(u32x4*)(og + (size_t)(ot * 16 + l15) * 256 + w * 32 + lg * 8) = sv;
    }
}

// ============================ unified proj ============================
// blocks 0..4095: kv half-images (img=bid>>1, half=bid&1); 4096..6143: q halves
__global__ __launch_bounds__(256) void proj_kernel(
    const float* __restrict__ qq, const float* __restrict__ kvg,
    const float* __restrict__ Wq, const float* __restrict__ bq,
    const float* __restrict__ Wk, const float* __restrict__ bk,
    const float* __restrict__ Wv, const float* __restrict__ bv,
    unsigned short* __restrict__ qbf, unsigned short* __restrict__ kbf,
    unsigned short* __restrict__ vbf)
{
    __shared__ unsigned short XT[128 * TS];   // [p][c] transposed, 16.9 KB
    const int tid = threadIdx.x;
    const int w = tid >> 6, lane = tid & 63;
    const int l15 = lane & 15, lg = lane >> 4;
    const int l7 = lane & 7, lh8 = lane >> 3;
    const int bid = blockIdx.x;
    const bool dual = (bid < 4096);

    const float* xg;
    unsigned short* o1;
    unsigned short* o2 = nullptr;
    if (dual) {
        const int img = bid >> 1, half = bid & 1;
        xg = kvg + (size_t)img * 16384 + half * 128;
        o1 = kbf + (size_t)img * 16384 + half * 128;
        o2 = vbf + (size_t)img * 16384 + half * 128;
    } else {
        const int n = bid - 4096;
        const int img = n >> 1, half = n & 1;
        xg = qq + (size_t)img * 16384 + half * 128;
        o1 = qbf + (size_t)img * 16384 + half * 128;
    }

    bf16x8 bf1[4][2]; float bias1[4];
    load_wfrags(dual ? Wk : Wq, dual ? bk : bq, l15, lg, bf1, bias1);

    // stage X -> XT[p][c] (local p in [0,128)); wave w owns p-band [w*32,+32)
    const int pq = w * 32 + l7 * 4;           // this thread's pixel quad
#pragma unroll
    for (int it = 0; it < 2; ++it) {
        const int c0 = it * 32 + lh8 * 4;
        f32x4 r0 = __builtin_nontemporal_load((const f32x4*)(xg + (size_t)(c0 + 0) * 256 + pq));
        f32x4 r1 = __builtin_nontemporal_load((const f32x4*)(xg + (size_t)(c0 + 1) * 256 + pq));
        f32x4 r2 = __builtin_nontemporal_load((const f32x4*)(xg + (size_t)(c0 + 2) * 256 + pq));
        f32x4 r3 = __builtin_nontemporal_load((const f32x4*)(xg + (size_t)(c0 + 3) * 256 + pq));
#pragma unroll
        for (int j = 0; j < 4; ++j) {
            u32x2 dd;
            dd[0] = pk2(r0[j], r1[j]);
            dd[1] = pk2(r2[j], r3[j]);
            *(u32x2*)(&XT[(pq + j) * TS + c0]) = dd;
        }
    }
    // NO barrier: wave w staged exactly the p-band it reads below.

    // A-frags [u][ks], row-permuted: prow = w*32 + (l15>>2)*8 + u*4 + (l15&3)
    bf16x8 afr[2][2];
#pragma unroll
    for (int u = 0; u < 2; ++u) {
        const int prow = w * 32 + (l15 >> 2) * 8 + u * 4 + (l15 & 3);
#pragma unroll
        for (int ks = 0; ks < 2; ++ks)
            afr[u][ks] = *(const bf16x8*)(&XT[prow * TS + ks * 32 + lg * 8]);
    }

    emit_half(afr, bf1, bias1, w, l15, lg, o1);
    if (dual) {
        load_wfrags(Wv, bv, l15, lg, bf1, bias1);   // reuse regs, L2-hot
        emit_half(afr, bf1, bias1, w, l15, lg, o2);
    }
}

// ============================ sim (Q.K^T partials, K-split x4) ============================
// r1/r5-proven version: grid 256 = (bh 64) x (ks 4); block 128 (2 waves)
__global__ __launch_bounds__(128) void sim_kernel(
    const unsigned short* __restrict__ qbf, const unsigned short* __restrict__ kbf,
    float* __restrict__ partial)
{
    const int tid = threadIdx.x;
    const int w = tid >> 6, lane = tid & 63;
    const int l31 = lane & 31, lh = lane >> 5;
    const int bh = blockIdx.x & 63, ks = blockIdx.x >> 6;
    const int b = bh >> 2, head = bh & 3;
    const int t0 = w * 64;

    const unsigned short* qbase = qbf + (size_t)b * 64 * 16384 + head * 4096;
    const unsigned short* kbase = kbf + (size_t)b * 128 * 16384 + head * 4096;

    f32x16 acc00 = zero16(), acc01 = zero16(), acc10 = zero16(), acc11 = zero16();
    const int kk0 = ks * 1024;
    for (int kk = 0; kk < 64; ++kk) {
        int k = kk0 + kk * 16 + lh * 8;
        bf16x8 a0 = *(const bf16x8*)(qbase + (size_t)(l31)      * 16384 + k);
        bf16x8 a1 = *(const bf16x8*)(qbase + (size_t)(l31 + 32) * 16384 + k);
        bf16x8 b0 = *(const bf16x8*)(kbase + (size_t)(t0 + l31)      * 16384 + k);
        bf16x8 b1 = *(const bf16x8*)(kbase + (size_t)(t0 + 32 + l31) * 16384 + k);
        acc00 = __builtin_amdgcn_mfma_f32_32x32x16_bf16(a0, b0, acc00, 0, 0, 0);
        acc01 = __builtin_amdgcn_mfma_f32_32x32x16_bf16(a0, b1, acc01, 0, 0, 0);
        acc10 = __builtin_amdgcn_mfma_f32_32x32x16_bf16(a1, b0, acc10, 0, 0, 0);
        acc11 = __builtin_amdgcn_mfma_f32_32x32x16_bf16(a1, b1, acc11, 0, 0, 0);
    }

    float* pb = partial + ((size_t)ks * 4096 + (size_t)bh * 64) * 128;
#pragma unroll
    for (int r = 0; r < 16; ++r) {
        int kqr = (r & 3) + 8 * (r >> 2) + 4 * lh;
        pb[(kqr)      * 128 + t0 + l31]      = acc00[r];
        pb[(kqr)      * 128 + t0 + 32 + l31] = acc01[r];
        pb[(kqr + 32) * 128 + t0 + l31]      = acc10[r];
        pb[(kqr + 32) * 128 + t0 + 32 + l31] = acc11[r];
    }
}

// ============================ softmax ============================
__global__ __launch_bounds__(256) void softmax_kernel(
    const float* __restrict__ partial, float* __restrict__ sim_out,
    unsigned short* __restrict__ pbf)
{
    const int tid = threadIdx.x;
    const int w = tid >> 6, lane = tid & 63;
    const int row = blockIdx.x * 4 + w;

    float x0 = 0.f, x1 = 0.f;
#pragma unroll
    for (int s = 0; s < 4; ++s) {
        x0 += partial[((size_t)s * 4096 + row) * 128 + lane];
        x1 += partial[((size_t)s * 4096 + row) * 128 + 64 + lane];
    }
    const float scale = 1.0f / 64.0f;
    x0 *= scale; x1 *= scale;
    float m = fmaxf(x0, x1);
#pragma unroll
    for (int off = 32; off; off >>= 1) m = fmaxf(m, __shfl_xor(m, off));
    float e0 = __expf(x0 - m), e1 = __expf(x1 - m);
    float s = e0 + e1;
#pragma unroll
    for (int off = 32; off; off >>= 1) s += __shfl_xor(s, off);
    float inv = 1.0f / s;
    float p0 = e0 * inv, p1 = e1 * inv;
    sim_out[(size_t)row * 128 + lane]      = p0;
    sim_out[(size_t)row * 128 + 64 + lane] = p1;
    pbf[(size_t)row * 128 + lane]      = f2bf(p0);
    pbf[(size_t)row * 128 + 64 + lane] = f2bf(p1);
}

// ============================ PV (natural V, transpose-on-read) ============================
__global__ __launch_bounds__(256) void pv_kernel(
    const unsigned short* __restrict__ pbf, const unsigned short* __restrict__ vbf,
    float* __restrict__ outp)
{
    const int tid = threadIdx.x;
    const int w = tid >> 6, lane = tid & 63;
    const int l31 = lane & 31, lh = lane >> 5;
    const int bh = blockIdx.x >> 4, cb = blockIdx.x & 15;
    const int b = bh >> 2, h = bh & 3;
    const int ch = h * 16 + cb;
    const int p0 = w * 64;

    const unsigned short* pb = pbf + (size_t)bh * 64 * 128;
    const unsigned short* vb = vbf + (size_t)b * 128 * 16384 + (size_t)ch * 256;

    f32x16 acc00 = zero16(), acc01 = zero16(), acc10 = zero16(), acc11 = zero16();
    for (int kk = 0; kk < 8; ++kk) {
        const int t0 = kk * 16;
        bf16x8 a0 = *(const bf16x8*)(pb + (size_t)l31 * 128 + t0 + lh * 8);
        bf16x8 a1 = *(const bf16x8*)(pb + (size_t)(l31 + 32) * 128 + t0 + lh * 8);
        bf16x8 b0, b1;
#pragma unroll
        for (int j = 0; j < 8; ++j) {
            const unsigned short* vr = vb + (size_t)(t0 + lh * 8 + j) * 16384;
            b0[j] = (short)vr[p0 + l31];
            b1[j] = (short)vr[p0 + 32 + l31];
        }
        acc00 = __builtin_amdgcn_mfma_f32_32x32x16_bf16(a0, b0, acc00, 0, 0, 0);
        acc01 = __builtin_amdgcn_mfma_f32_32x32x16_bf16(a0, b1, acc01, 0, 0, 0);
        acc10 = __builtin_amdgcn_mfma_f32_32x32x16_bf16(a1, b0, acc10, 0, 0, 0);
        acc11 = __builtin_amdgcn_mfma_f32_32x32x16_bf16(a1, b1, acc11, 0, 0, 0);
    }

    float* ob = outp + (size_t)b * 64 * 16384 + (size_t)ch * 256;
#pragma unroll
    for (int r = 0; r < 16; ++r) {
        int kqr = (r & 3) + 8 * (r >> 2) + 4 * lh;
        ob[(size_t)(kqr)      * 16384 + p0 + l31]      = acc00[r];
        ob[(size_t)(kqr)      * 16384 + p0 + 32 + l31] = acc01[r];
        ob[(size_t)(kqr + 32) * 16384 + p0 + l31]      = acc10[r];
        ob[(size_t)(kqr + 32) * 16384 + p0 + 32 + l31] = acc11[r];
    }
}

// ============================ launch ============================
extern "C" void kernel_launch(void* const* d_in, const int* in_sizes, int n_in,
                              void* d_out, int out_size, void* d_ws, size_t ws_size,
                              hipStream_t stream)
{
    const float* qq = (const float*)d_in[0];
    const float* kv = (const float*)d_in[1];
    const float* Wq = (const float*)d_in[2];
    const float* bq = (const float*)d_in[3];
    const float* Wk = (const float*)d_in[4];
    const float* bk = (const float*)d_in[5];
    const float* Wv = (const float*)d_in[6];
    const float* bv = (const float*)d_in[7];

    float* outp    = (float*)d_out;
    float* sim_out = outp + (size_t)16777216;

    char* ws = (char*)d_ws;
    unsigned short* qbf     = (unsigned short*)(ws);
    unsigned short* kbf     = (unsigned short*)(ws + 33554432);
    unsigned short* vbf     = (unsigned short*)(ws + 100663296);
    float*          partial = (float*)         (ws + 167772160);
    unsigned short* pbf     = (unsigned short*)(ws + 176160768);
    (void)in_sizes; (void)n_in; (void)out_size; (void)ws_size;

    proj_kernel   <<<dim3(6144), dim3(256), 0, stream>>>(qq, kv, Wq, bq, Wk, bk, Wv, bv,
                                                         qbf, kbf, vbf);
    sim_kernel    <<<dim3(256),  dim3(128), 0, stream>>>(qbf, kbf, partial);
    softmax_kernel<<<dim3(1024), dim3(256), 0, stream>>>(partial, sim_out, pbf);
    pv_kernel     <<<dim3(1024), dim3(256), 0, stream>>>(pbf, vbf, outp);
}

// Round 14
// 141.004 us; speedup vs baseline: 1.5119x; 1.1050x over previous
//
#include <hip/hip_runtime.h>
#include <hip/hip_bf16.h>
#include <stdint.h>
#include <stddef.h>

#define DEVI __device__ __forceinline__

typedef __attribute__((ext_vector_type(8)))  short bf16x8;
typedef __attribute__((ext_vector_type(4)))  float f32x4;
typedef __attribute__((ext_vector_type(16))) float f32x16;
typedef __attribute__((ext_vector_type(2)))  unsigned u32x2;
typedef __attribute__((ext_vector_type(4)))  unsigned u32x4;

DEVI unsigned short f2bf(float f) {
    __hip_bfloat16 h = __float2bfloat16(f);   // RNE
    union { __hip_bfloat16 h; unsigned short u; } v; v.h = h; return v.u;
}
// paired convert -> single v_cvt_pk_bf16_f32 (lo in bits[15:0])
DEVI unsigned pk2(float lo, float hi) {
    union { __hip_bfloat162 h2; unsigned u; } v;
    v.h2 = __float22bfloat162_rn(float2{lo, hi});
    return v.u;
}
DEVI f32x4 zero4() { f32x4 z; z[0] = z[1] = z[2] = z[3] = 0.f; return z; }
DEVI f32x16 zero16() {
    f32x16 z;
#pragma unroll
    for (int i = 0; i < 16; ++i) z[i] = 0.f;
    return z;
}

// ---------------------------------------------------------------------------
// ws layout:
//   qbf [1024][64][256] bf16 @ 0           natural
//   kbf [2048][64][256] bf16 @ 33554432    natural
//   vbf [2048][64][256] bf16 @ 100663296   natural
//   partial [4][4096][128] f32 @ 167772160
//   (pbf slot unused since softmax folded into pv)
// ---------------------------------------------------------------------------
// proj v5 (r11 verbatim — measured optimum 86 us):
//   - X staged TRANSPOSED [p][c] (stride 66) via per-thread 4x4 reg transpose
//     (nt loads); wave w stages & reads only its p-band -> zero barriers
//   - A-frag = one ds_read_b128; row-permuted so lane owns 8 contiguous px
//   - direct u32x4 stores (full 64B lines); paired cvt via v_cvt_pk_bf16_f32
// ---------------------------------------------------------------------------

#define TS 66   // transposed X stride in shorts: [256 p][66]

DEVI void load_wfrags(const float* __restrict__ W, const float* __restrict__ B,
                      int l15, int lg, bf16x8 (&bf)[4][2], float (&bias)[4]) {
#pragma unroll
    for (int ot = 0; ot < 4; ++ot) {
        const int o = ot * 16 + l15;
        bias[ot] = B[o];
#pragma unroll
        for (int ks = 0; ks < 2; ++ks) {
            const float* wp = W + o * 64 + ks * 32 + lg * 8;
            f32x4 w0 = *(const f32x4*)wp, w1 = *(const f32x4*)(wp + 4);
            union { bf16x8 a; u32x4 u; } cv;
            cv.u[0] = pk2(w0[0], w0[1]);
            cv.u[1] = pk2(w0[2], w0[3]);
            cv.u[2] = pk2(w1[0], w1[1]);
            cv.u[3] = pk2(w1[2], w1[3]);
            bf[ot][ks] = cv.a;
        }
    }
}

// 32 MFMA -> 8 dwordx4 full-line stores (no LDS staging)
DEVI void emit_direct(const bf16x8 (&afr)[2][2][2], const bf16x8 (&bf)[4][2],
                      const float (&bias)[4], int w, int l15, int lg,
                      unsigned short* __restrict__ og) {
#pragma unroll
    for (int pt2 = 0; pt2 < 2; ++pt2) {
#pragma unroll
        for (int ot = 0; ot < 4; ++ot) {
            f32x4 a0 = zero4(), a1 = zero4();
            a0 = __builtin_amdgcn_mfma_f32_16x16x32_bf16(afr[pt2][0][0], bf[ot][0], a0, 0, 0, 0);
            a0 = __builtin_amdgcn_mfma_f32_16x16x32_bf16(afr[pt2][0][1], bf[ot][1], a0, 0, 0, 0);
            a1 = __builtin_amdgcn_mfma_f32_16x16x32_bf16(afr[pt2][1][0], bf[ot][0], a1, 0, 0, 0);
            a1 = __builtin_amdgcn_mfma_f32_16x16x32_bf16(afr[pt2][1][1], bf[ot][1], a1, 0, 0, 0);
            const float b = bias[ot];
            u32x4 sv;
            sv[0] = pk2(a0[0] + b, a0[1] + b);
            sv[1] = pk2(a0[2] + b, a0[3] + b);
            sv[2] = pk2(a1[0] + b, a1[1] + b);
            sv[3] = pk2(a1[2] + b, a1[3] + b);
            *(u32x4*)(og + (size_t)(ot * 16 + l15) * 256 + w * 64 + pt2 * 32 + lg * 8) = sv;
        }
    }
}

// ============================ unified proj ============================
// blocks 0..2047: kv (k+v); 2048..3071: q
__global__ __launch_bounds__(256, 4) void proj_kernel(
    const float* __restrict__ qq, const float* __restrict__ kvg,
    const float* __restrict__ Wq, const float* __restrict__ bq,
    const float* __restrict__ Wk, const float* __restrict__ bk,
    const float* __restrict__ Wv, const float* __restrict__ bv,
    unsigned short* __restrict__ qbf, unsigned short* __restrict__ kbf,
    unsigned short* __restrict__ vbf)
{
    __shared__ unsigned short XT[256 * TS];   // [p][c] transposed
    const int tid = threadIdx.x;
    const int w = tid >> 6, lane = tid & 63;
    const int l15 = lane & 15, lg = lane >> 4;
    const int bid = blockIdx.x;
    const bool dual = (bid < 2048);
    const float* xg = dual ? (kvg + (size_t)bid * 16384)
                           : (qq + (size_t)(bid - 2048) * 16384);
    unsigned short* o1 = dual ? (kbf + (size_t)bid * 16384)
                              : (qbf + (size_t)(bid - 2048) * 16384);

    bf16x8 bf1[4][2]; float bias1[4];
    load_wfrags(dual ? Wk : Wq, dual ? bk : bq, l15, lg, bf1, bias1);

    // stage X -> XT[p][c]: per it, nt-load 4x4 fp32 block, write 4 transposed cols
    const int pq = w * 64 + l15 * 4;          // this thread's pixel quad
#pragma unroll
    for (int it = 0; it < 4; ++it) {
        const int c0 = it * 16 + lg * 4;
        f32x4 r0 = __builtin_nontemporal_load((const f32x4*)(xg + (size_t)(c0 + 0) * 256 + pq));
        f32x4 r1 = __builtin_nontemporal_load((const f32x4*)(xg + (size_t)(c0 + 1) * 256 + pq));
        f32x4 r2 = __builtin_nontemporal_load((const f32x4*)(xg + (size_t)(c0 + 2) * 256 + pq));
        f32x4 r3 = __builtin_nontemporal_load((const f32x4*)(xg + (size_t)(c0 + 3) * 256 + pq));
#pragma unroll
        for (int j = 0; j < 4; ++j) {
            u32x2 dd;
            dd[0] = pk2(r0[j], r1[j]);
            dd[1] = pk2(r2[j], r3[j]);
            *(u32x2*)(&XT[(pq + j) * TS + c0]) = dd;
        }
    }
    // NO barrier: wave w staged exactly the p-band it reads below.

    // A-frags [pt2][u][ks], row-permuted so lane owns 8 contiguous pixels:
    // p_row = w*64 + pt2*32 + (l15>>2)*8 + u*4 + (l15&3)
    bf16x8 afr[2][2][2];
#pragma unroll
    for (int pt2 = 0; pt2 < 2; ++pt2)
#pragma unroll
        for (int u = 0; u < 2; ++u) {
            const int prow = w * 64 + pt2 * 32 + (l15 >> 2) * 8 + u * 4 + (l15 & 3);
#pragma unroll
            for (int ks = 0; ks < 2; ++ks)
                afr[pt2][u][ks] = *(const bf16x8*)(&XT[prow * TS + ks * 32 + lg * 8]);
        }

    emit_direct(afr, bf1, bias1, w, l15, lg, o1);
    if (dual) {
        load_wfrags(Wv, bv, l15, lg, bf1, bias1);   // reuse regs, L2-hot
        emit_direct(afr, bf1, bias1, w, l15, lg, vbf + (size_t)bid * 16384);
    }
}

// ============================ sim (Q.K^T partials, K-split x4) ============================
// r1/r5-proven version: grid 256 = (bh 64) x (ks 4); block 128 (2 waves)
__global__ __launch_bounds__(128) void sim_kernel(
    const unsigned short* __restrict__ qbf, const unsigned short* __restrict__ kbf,
    float* __restrict__ partial)
{
    const int tid = threadIdx.x;
    const int w = tid >> 6, lane = tid & 63;
    const int l31 = lane & 31, lh = lane >> 5;
    const int bh = blockIdx.x & 63, ks = blockIdx.x >> 6;
    const int b = bh >> 2, head = bh & 3;
    const int t0 = w * 64;

    const unsigned short* qbase = qbf + (size_t)b * 64 * 16384 + head * 4096;
    const unsigned short* kbase = kbf + (size_t)b * 128 * 16384 + head * 4096;

    f32x16 acc00 = zero16(), acc01 = zero16(), acc10 = zero16(), acc11 = zero16();
    const int kk0 = ks * 1024;
    for (int kk = 0; kk < 64; ++kk) {
        int k = kk0 + kk * 16 + lh * 8;
        bf16x8 a0 = *(const bf16x8*)(qbase + (size_t)(l31)      * 16384 + k);
        bf16x8 a1 = *(const bf16x8*)(qbase + (size_t)(l31 + 32) * 16384 + k);
        bf16x8 b0 = *(const bf16x8*)(kbase + (size_t)(t0 + l31)      * 16384 + k);
        bf16x8 b1 = *(const bf16x8*)(kbase + (size_t)(t0 + 32 + l31) * 16384 + k);
        acc00 = __builtin_amdgcn_mfma_f32_32x32x16_bf16(a0, b0, acc00, 0, 0, 0);
        acc01 = __builtin_amdgcn_mfma_f32_32x32x16_bf16(a0, b1, acc01, 0, 0, 0);
        acc10 = __builtin_amdgcn_mfma_f32_32x32x16_bf16(a1, b0, acc10, 0, 0, 0);
        acc11 = __builtin_amdgcn_mfma_f32_32x32x16_bf16(a1, b1, acc11, 0, 0, 0);
    }

    float* pb = partial + ((size_t)ks * 4096 + (size_t)bh * 64) * 128;
#pragma unroll
    for (int r = 0; r < 16; ++r) {
        int kqr = (r & 3) + 8 * (r >> 2) + 4 * lh;
        pb[(kqr)      * 128 + t0 + l31]      = acc00[r];
        pb[(kqr)      * 128 + t0 + 32 + l31] = acc01[r];
        pb[(kqr + 32) * 128 + t0 + l31]      = acc10[r];
        pb[(kqr + 32) * 128 + t0 + 32 + l31] = acc11[r];
    }
}

// ============================ PV with fused softmax ============================
// grid 1024 = cb(16) x bh(64), bid = cb*64 + bh so the 16 cb-siblings of a bh
// are 64 apart -> same XCD (64 % 8 == 0) -> partial reads L2-local.
// Phase 1: block recomputes softmax for its bh (4 waves x 16 rows), stages
//          P bf16 in LDS [64][136] (272B stride: 4-way bank alias, OK);
//          cb==0 block also writes sim_out f32.
// Phase 2: PV MFMA loop, A-frags from LDS P, V transpose-on-read (r11 style).
#define PS 136
__global__ __launch_bounds__(256) void pv_kernel(
    const float* __restrict__ partial, const unsigned short* __restrict__ vbf,
    float* __restrict__ outp, float* __restrict__ sim_out)
{
    __shared__ unsigned short P[64 * PS];
    const int tid = threadIdx.x;
    const int w = tid >> 6, lane = tid & 63;
    const int l31 = lane & 31, lh = lane >> 5;
    const int bh = blockIdx.x & 63, cb = blockIdx.x >> 6;
    const int b = bh >> 2, h = bh & 3;
    const int ch = h * 16 + cb;
    const int p0 = w * 64;

    // ---- phase 1: softmax (each wave: 16 rows of this bh)
    const float scale = 1.0f / 64.0f;
#pragma unroll 4
    for (int i = 0; i < 16; ++i) {
        const int r64 = w * 16 + i;
        const size_t row = (size_t)bh * 64 + r64;
        float x0 = 0.f, x1 = 0.f;
#pragma unroll
        for (int s = 0; s < 4; ++s) {
            x0 += partial[((size_t)s * 4096 + row) * 128 + lane];
            x1 += partial[((size_t)s * 4096 + row) * 128 + 64 + lane];
        }
        x0 *= scale; x1 *= scale;
        float m = fmaxf(x0, x1);
#pragma unroll
        for (int off = 32; off; off >>= 1) m = fmaxf(m, __shfl_xor(m, off));
        float e0 = __expf(x0 - m), e1 = __expf(x1 - m);
        float s = e0 + e1;
#pragma unroll
        for (int off = 32; off; off >>= 1) s += __shfl_xor(s, off);
        float inv = 1.0f / s;
        float p0v = e0 * inv, p1v = e1 * inv;
        if (cb == 0) {
            sim_out[row * 128 + lane]      = p0v;
            sim_out[row * 128 + 64 + lane] = p1v;
        }
        P[r64 * PS + lane]      = f2bf(p0v);
        P[r64 * PS + 64 + lane] = f2bf(p1v);
    }
    __syncthreads();

    // ---- phase 2: PV (A-frags from LDS P; V natural, transpose-on-read)
    const unsigned short* vb = vbf + (size_t)b * 128 * 16384 + (size_t)ch * 256;

    f32x16 acc00 = zero16(), acc01 = zero16(), acc10 = zero16(), acc11 = zero16();
    for (int kk = 0; kk < 8; ++kk) {
        const int t0 = kk * 16;
        bf16x8 a0 = *(const bf16x8*)(&P[l31 * PS + t0 + lh * 8]);
        bf16x8 a1 = *(const bf16x8*)(&P[(l31 + 32) * PS + t0 + lh * 8]);
        bf16x8 b0, b1;
#pragma unroll
        for (int j = 0; j < 8; ++j) {
            const unsigned short* vr = vb + (size_t)(t0 + lh * 8 + j) * 16384;
            b0[j] = (short)vr[p0 + l31];
            b1[j] = (short)vr[p0 + 32 + l31];
        }
        acc00 = __builtin_amdgcn_mfma_f32_32x32x16_bf16(a0, b0, acc00, 0, 0, 0);
        acc01 = __builtin_amdgcn_mfma_f32_32x32x16_bf16(a0, b1, acc01, 0, 0, 0);
        acc10 = __builtin_amdgcn_mfma_f32_32x32x16_bf16(a1, b0, acc10, 0, 0, 0);
        acc11 = __builtin_amdgcn_mfma_f32_32x32x16_bf16(a1, b1, acc11, 0, 0, 0);
    }

    float* ob = outp + (size_t)b * 64 * 16384 + (size_t)ch * 256;
#pragma unroll
    for (int r = 0; r < 16; ++r) {
        int kqr = (r & 3) + 8 * (r >> 2) + 4 * lh;
        ob[(size_t)(kqr)      * 16384 + p0 + l31]      = acc00[r];
        ob[(size_t)(kqr)      * 16384 + p0 + 32 + l31] = acc01[r];
        ob[(size_t)(kqr + 32) * 16384 + p0 + l31]      = acc10[r];
        ob[(size_t)(kqr + 32) * 16384 + p0 + 32 + l31] = acc11[r];
    }
}

// ============================ launch ============================
extern "C" void kernel_launch(void* const* d_in, const int* in_sizes, int n_in,
                              void* d_out, int out_size, void* d_ws, size_t ws_size,
                              hipStream_t stream)
{
    const float* qq = (const float*)d_in[0];
    const float* kv = (const float*)d_in[1];
    const float* Wq = (const float*)d_in[2];
    const float* bq = (const float*)d_in[3];
    const float* Wk = (const float*)d_in[4];
    const float* bk = (const float*)d_in[5];
    const float* Wv = (const float*)d_in[6];
    const float* bv = (const float*)d_in[7];

    float* outp    = (float*)d_out;
    float* sim_out = outp + (size_t)16777216;

    char* ws = (char*)d_ws;
    unsigned short* qbf     = (unsigned short*)(ws);
    unsigned short* kbf     = (unsigned short*)(ws + 33554432);
    unsigned short* vbf     = (unsigned short*)(ws + 100663296);
    float*          partial = (float*)         (ws + 167772160);
    (void)in_sizes; (void)n_in; (void)out_size; (void)ws_size;

    proj_kernel<<<dim3(3072), dim3(256), 0, stream>>>(qq, kv, Wq, bq, Wk, bk, Wv, bv,
                                                      qbf, kbf, vbf);
    sim_kernel <<<dim3(256),  dim3(128), 0, stream>>>(qbf, kbf, partial);
    pv_kernel  <<<dim3(1024), dim3(256), 0, stream>>>(partial, vbf, outp, sim_out);
}

// Round 15
// 134.080 us; speedup vs baseline: 1.5900x; 1.0516x over previous
//
#include <hip/hip_runtime.h>
#include <hip/hip_bf16.h>
#include <stdint.h>
#include <stddef.h>

#define DEVI __device__ __forceinline__

typedef __attribute__((ext_vector_type(8)))  short bf16x8;
typedef __attribute__((ext_vector_type(4)))  float f32x4;
typedef __attribute__((ext_vector_type(16))) float f32x16;
typedef __attribute__((ext_vector_type(2)))  unsigned u32x2;
typedef __attribute__((ext_vector_type(4)))  unsigned u32x4;

DEVI unsigned short f2bf(float f) {
    __hip_bfloat16 h = __float2bfloat16(f);   // RNE
    union { __hip_bfloat16 h; unsigned short u; } v; v.h = h; return v.u;
}
// paired convert -> single v_cvt_pk_bf16_f32 (lo in bits[15:0])
DEVI unsigned pk2(float lo, float hi) {
    union { __hip_bfloat162 h2; unsigned u; } v;
    v.h2 = __float22bfloat162_rn(float2{lo, hi});
    return v.u;
}
DEVI f32x4 zero4() { f32x4 z; z[0] = z[1] = z[2] = z[3] = 0.f; return z; }
DEVI f32x16 zero16() {
    f32x16 z;
#pragma unroll
    for (int i = 0; i < 16; ++i) z[i] = 0.f;
    return z;
}

// ---------------------------------------------------------------------------
// ws layout:
//   qbf [1024][64][256] bf16 @ 0           natural
//   kbf [2048][64][256] bf16 @ 33554432    natural
//   vbf [2048][64][256] bf16 @ 100663296   natural
//   partial [4][4096][128] f32 @ 167772160
//   pbf [4096][128] bf16 @ 176160768
// ---------------------------------------------------------------------------
// r11 configuration verbatim — measured optimum (134.1 us total).
// proj: zero-barrier transposed-LDS, wave-private p-bands, pk2 converts,
//       nt X-loads, full-line u32x4 stores. 86 us @ ~3 TB/s combined.
// sim:  grid-256 K-split-4 (98 MB traffic; grid-1024 kq-split variant
//       measured +20 us total in r6 — do not swap).
// softmax + pv separate (fusion measured +7 us in r14 — do not fuse).
// ---------------------------------------------------------------------------

#define TS 66   // transposed X stride in shorts: [256 p][66]

DEVI void load_wfrags(const float* __restrict__ W, const float* __restrict__ B,
                      int l15, int lg, bf16x8 (&bf)[4][2], float (&bias)[4]) {
#pragma unroll
    for (int ot = 0; ot < 4; ++ot) {
        const int o = ot * 16 + l15;
        bias[ot] = B[o];
#pragma unroll
        for (int ks = 0; ks < 2; ++ks) {
            const float* wp = W + o * 64 + ks * 32 + lg * 8;
            f32x4 w0 = *(const f32x4*)wp, w1 = *(const f32x4*)(wp + 4);
            union { bf16x8 a; u32x4 u; } cv;
            cv.u[0] = pk2(w0[0], w0[1]);
            cv.u[1] = pk2(w0[2], w0[3]);
            cv.u[2] = pk2(w1[0], w1[1]);
            cv.u[3] = pk2(w1[2], w1[3]);
            bf[ot][ks] = cv.a;
        }
    }
}

// 32 MFMA -> 8 dwordx4 full-line stores (no LDS staging)
DEVI void emit_direct(const bf16x8 (&afr)[2][2][2], const bf16x8 (&bf)[4][2],
                      const float (&bias)[4], int w, int l15, int lg,
                      unsigned short* __restrict__ og) {
#pragma unroll
    for (int pt2 = 0; pt2 < 2; ++pt2) {
#pragma unroll
        for (int ot = 0; ot < 4; ++ot) {
            f32x4 a0 = zero4(), a1 = zero4();
            a0 = __builtin_amdgcn_mfma_f32_16x16x32_bf16(afr[pt2][0][0], bf[ot][0], a0, 0, 0, 0);
            a0 = __builtin_amdgcn_mfma_f32_16x16x32_bf16(afr[pt2][0][1], bf[ot][1], a0, 0, 0, 0);
            a1 = __builtin_amdgcn_mfma_f32_16x16x32_bf16(afr[pt2][1][0], bf[ot][0], a1, 0, 0, 0);
            a1 = __builtin_amdgcn_mfma_f32_16x16x32_bf16(afr[pt2][1][1], bf[ot][1], a1, 0, 0, 0);
            const float b = bias[ot];
            u32x4 sv;
            sv[0] = pk2(a0[0] + b, a0[1] + b);
            sv[1] = pk2(a0[2] + b, a0[3] + b);
            sv[2] = pk2(a1[0] + b, a1[1] + b);
            sv[3] = pk2(a1[2] + b, a1[3] + b);
            *(u32x4*)(og + (size_t)(ot * 16 + l15) * 256 + w * 64 + pt2 * 32 + lg * 8) = sv;
        }
    }
}

// ============================ unified proj ============================
// blocks 0..2047: kv (k+v); 2048..3071: q
__global__ __launch_bounds__(256, 4) void proj_kernel(
    const float* __restrict__ qq, const float* __restrict__ kvg,
    const float* __restrict__ Wq, const float* __restrict__ bq,
    const float* __restrict__ Wk, const float* __restrict__ bk,
    const float* __restrict__ Wv, const float* __restrict__ bv,
    unsigned short* __restrict__ qbf, unsigned short* __restrict__ kbf,
    unsigned short* __restrict__ vbf)
{
    __shared__ unsigned short XT[256 * TS];   // [p][c] transposed
    const int tid = threadIdx.x;
    const int w = tid >> 6, lane = tid & 63;
    const int l15 = lane & 15, lg = lane >> 4;
    const int bid = blockIdx.x;
    const bool dual = (bid < 2048);
    const float* xg = dual ? (kvg + (size_t)bid * 16384)
                           : (qq + (size_t)(bid - 2048) * 16384);
    unsigned short* o1 = dual ? (kbf + (size_t)bid * 16384)
                              : (qbf + (size_t)(bid - 2048) * 16384);

    bf16x8 bf1[4][2]; float bias1[4];
    load_wfrags(dual ? Wk : Wq, dual ? bk : bq, l15, lg, bf1, bias1);

    // stage X -> XT[p][c]: per it, nt-load 4x4 fp32 block, write 4 transposed cols
    const int pq = w * 64 + l15 * 4;          // this thread's pixel quad
#pragma unroll
    for (int it = 0; it < 4; ++it) {
        const int c0 = it * 16 + lg * 4;
        f32x4 r0 = __builtin_nontemporal_load((const f32x4*)(xg + (size_t)(c0 + 0) * 256 + pq));
        f32x4 r1 = __builtin_nontemporal_load((const f32x4*)(xg + (size_t)(c0 + 1) * 256 + pq));
        f32x4 r2 = __builtin_nontemporal_load((const f32x4*)(xg + (size_t)(c0 + 2) * 256 + pq));
        f32x4 r3 = __builtin_nontemporal_load((const f32x4*)(xg + (size_t)(c0 + 3) * 256 + pq));
#pragma unroll
        for (int j = 0; j < 4; ++j) {
            u32x2 dd;
            dd[0] = pk2(r0[j], r1[j]);
            dd[1] = pk2(r2[j], r3[j]);
            *(u32x2*)(&XT[(pq + j) * TS + c0]) = dd;
        }
    }
    // NO barrier: wave w staged exactly the p-band it reads below.

    // A-frags [pt2][u][ks], row-permuted so lane owns 8 contiguous pixels:
    // p_row = w*64 + pt2*32 + (l15>>2)*8 + u*4 + (l15&3)
    bf16x8 afr[2][2][2];
#pragma unroll
    for (int pt2 = 0; pt2 < 2; ++pt2)
#pragma unroll
        for (int u = 0; u < 2; ++u) {
            const int prow = w * 64 + pt2 * 32 + (l15 >> 2) * 8 + u * 4 + (l15 & 3);
#pragma unroll
            for (int ks = 0; ks < 2; ++ks)
                afr[pt2][u][ks] = *(const bf16x8*)(&XT[prow * TS + ks * 32 + lg * 8]);
        }

    emit_direct(afr, bf1, bias1, w, l15, lg, o1);
    if (dual) {
        load_wfrags(Wv, bv, l15, lg, bf1, bias1);   // reuse regs, L2-hot
        emit_direct(afr, bf1, bias1, w, l15, lg, vbf + (size_t)bid * 16384);
    }
}

// ============================ sim (Q.K^T partials, K-split x4) ============================
// r1/r5-proven version: grid 256 = (bh 64) x (ks 4); block 128 (2 waves)
__global__ __launch_bounds__(128) void sim_kernel(
    const unsigned short* __restrict__ qbf, const unsigned short* __restrict__ kbf,
    float* __restrict__ partial)
{
    const int tid = threadIdx.x;
    const int w = tid >> 6, lane = tid & 63;
    const int l31 = lane & 31, lh = lane >> 5;
    const int bh = blockIdx.x & 63, ks = blockIdx.x >> 6;
    const int b = bh >> 2, head = bh & 3;
    const int t0 = w * 64;

    const unsigned short* qbase = qbf + (size_t)b * 64 * 16384 + head * 4096;
    const unsigned short* kbase = kbf + (size_t)b * 128 * 16384 + head * 4096;

    f32x16 acc00 = zero16(), acc01 = zero16(), acc10 = zero16(), acc11 = zero16();
    const int kk0 = ks * 1024;
    for (int kk = 0; kk < 64; ++kk) {
        int k = kk0 + kk * 16 + lh * 8;
        bf16x8 a0 = *(const bf16x8*)(qbase + (size_t)(l31)      * 16384 + k);
        bf16x8 a1 = *(const bf16x8*)(qbase + (size_t)(l31 + 32) * 16384 + k);
        bf16x8 b0 = *(const bf16x8*)(kbase + (size_t)(t0 + l31)      * 16384 + k);
        bf16x8 b1 = *(const bf16x8*)(kbase + (size_t)(t0 + 32 + l31) * 16384 + k);
        acc00 = __builtin_amdgcn_mfma_f32_32x32x16_bf16(a0, b0, acc00, 0, 0, 0);
        acc01 = __builtin_amdgcn_mfma_f32_32x32x16_bf16(a0, b1, acc01, 0, 0, 0);
        acc10 = __builtin_amdgcn_mfma_f32_32x32x16_bf16(a1, b0, acc10, 0, 0, 0);
        acc11 = __builtin_amdgcn_mfma_f32_32x32x16_bf16(a1, b1, acc11, 0, 0, 0);
    }

    float* pb = partial + ((size_t)ks * 4096 + (size_t)bh * 64) * 128;
#pragma unroll
    for (int r = 0; r < 16; ++r) {
        int kqr = (r & 3) + 8 * (r >> 2) + 4 * lh;
        pb[(kqr)      * 128 + t0 + l31]      = acc00[r];
        pb[(kqr)      * 128 + t0 + 32 + l31] = acc01[r];
        pb[(kqr + 32) * 128 + t0 + l31]      = acc10[r];
        pb[(kqr + 32) * 128 + t0 + 32 + l31] = acc11[r];
    }
}

// ============================ softmax ============================
__global__ __launch_bounds__(256) void softmax_kernel(
    const float* __restrict__ partial, float* __restrict__ sim_out,
    unsigned short* __restrict__ pbf)
{
    const int tid = threadIdx.x;
    const int w = tid >> 6, lane = tid & 63;
    const int row = blockIdx.x * 4 + w;

    float x0 = 0.f, x1 = 0.f;
#pragma unroll
    for (int s = 0; s < 4; ++s) {
        x0 += partial[((size_t)s * 4096 + row) * 128 + lane];
        x1 += partial[((size_t)s * 4096 + row) * 128 + 64 + lane];
    }
    const float scale = 1.0f / 64.0f;
    x0 *= scale; x1 *= scale;
    float m = fmaxf(x0, x1);
#pragma unroll
    for (int off = 32; off; off >>= 1) m = fmaxf(m, __shfl_xor(m, off));
    float e0 = __expf(x0 - m), e1 = __expf(x1 - m);
    float s = e0 + e1;
#pragma unroll
    for (int off = 32; off; off >>= 1) s += __shfl_xor(s, off);
    float inv = 1.0f / s;
    float p0 = e0 * inv, p1 = e1 * inv;
    sim_out[(size_t)row * 128 + lane]      = p0;
    sim_out[(size_t)row * 128 + 64 + lane] = p1;
    pbf[(size_t)row * 128 + lane]      = f2bf(p0);
    pbf[(size_t)row * 128 + 64 + lane] = f2bf(p1);
}

// ============================ PV (natural V, transpose-on-read) ============================
__global__ __launch_bounds__(256) void pv_kernel(
    const unsigned short* __restrict__ pbf, const unsigned short* __restrict__ vbf,
    float* __restrict__ outp)
{
    const int tid = threadIdx.x;
    const int w = tid >> 6, lane = tid & 63;
    const int l31 = lane & 31, lh = lane >> 5;
    const int bh = blockIdx.x >> 4, cb = blockIdx.x & 15;
    const int b = bh >> 2, h = bh & 3;
    const int ch = h * 16 + cb;
    const int p0 = w * 64;

    const unsigned short* pb = pbf + (size_t)bh * 64 * 128;
    const unsigned short* vb = vbf + (size_t)b * 128 * 16384 + (size_t)ch * 256;

    f32x16 acc00 = zero16(), acc01 = zero16(), acc10 = zero16(), acc11 = zero16();
    for (int kk = 0; kk < 8; ++kk) {
        const int t0 = kk * 16;
        bf16x8 a0 = *(const bf16x8*)(pb + (size_t)l31 * 128 + t0 + lh * 8);
        bf16x8 a1 = *(const bf16x8*)(pb + (size_t)(l31 + 32) * 128 + t0 + lh * 8);
        bf16x8 b0, b1;
#pragma unroll
        for (int j = 0; j < 8; ++j) {
            const unsigned short* vr = vb + (size_t)(t0 + lh * 8 + j) * 16384;
            b0[j] = (short)vr[p0 + l31];
            b1[j] = (short)vr[p0 + 32 + l31];
        }
        acc00 = __builtin_amdgcn_mfma_f32_32x32x16_bf16(a0, b0, acc00, 0, 0, 0);
        acc01 = __builtin_amdgcn_mfma_f32_32x32x16_bf16(a0, b1, acc01, 0, 0, 0);
        acc10 = __builtin_amdgcn_mfma_f32_32x32x16_bf16(a1, b0, acc10, 0, 0, 0);
        acc11 = __builtin_amdgcn_mfma_f32_32x32x16_bf16(a1, b1, acc11, 0, 0, 0);
    }

    float* ob = outp + (size_t)b * 64 * 16384 + (size_t)ch * 256;
#pragma unroll
    for (int r = 0; r < 16; ++r) {
        int kqr = (r & 3) + 8 * (r >> 2) + 4 * lh;
        ob[(size_t)(kqr)      * 16384 + p0 + l31]      = acc00[r];
        ob[(size_t)(kqr)      * 16384 + p0 + 32 + l31] = acc01[r];
        ob[(size_t)(kqr + 32) * 16384 + p0 + l31]      = acc10[r];
        ob[(size_t)(kqr + 32) * 16384 + p0 + 32 + l31] = acc11[r];
    }
}

// ============================ launch ============================
extern "C" void kernel_launch(void* const* d_in, const int* in_sizes, int n_in,
                              void* d_out, int out_size, void* d_ws, size_t ws_size,
                              hipStream_t stream)
{
    const float* qq = (const float*)d_in[0];
    const float* kv = (const float*)d_in[1];
    const float* Wq = (const float*)d_in[2];
    const float* bq = (const float*)d_in[3];
    const float* Wk = (const float*)d_in[4];
    const float* bk = (const float*)d_in[5];
    const float* Wv = (const float*)d_in[6];
    const float* bv = (const float*)d_in[7];

    float* outp    = (float*)d_out;
    float* sim_out = outp + (size_t)16777216;

    char* ws = (char*)d_ws;
    unsigned short* qbf     = (unsigned short*)(ws);
    unsigned short* kbf     = (unsigned short*)(ws + 33554432);
    unsigned short* vbf     = (unsigned short*)(ws + 100663296);
    float*          partial = (float*)         (ws + 167772160);
    unsigned short* pbf     = (unsigned short*)(ws + 176160768);
    (void)in_sizes; (void)n_in; (void)out_size; (void)ws_size;

    proj_kernel   <<<dim3(3072), dim3(256), 0, stream>>>(qq, kv, Wq, bq, Wk, bk, Wv, bv,
                                                         qbf, kbf, vbf);
    sim_kernel    <<<dim3(256),  dim3(128), 0, stream>>>(qbf, kbf, partial);
    softmax_kernel<<<dim3(1024), dim3(256), 0, stream>>>(partial, sim_out, pbf);
    pv_kernel     <<<dim3(1024), dim3(256), 0, stream>>>(pbf, vbf, outp);
}